// Round 17
// baseline (310.756 us; speedup 1.0000x reference)
//
#include <hip/hip_runtime.h>
#include <hip/hip_bf16.h>
#include <stdint.h>

#define B_ 32
#define S_ 2048
#define H_ 1024
#define U_ 1024

typedef __attribute__((ext_vector_type(8))) short short8;
typedef __attribute__((ext_vector_type(4))) float f32x4;

#define AS1 __attribute__((address_space(1)))
#define AS3 __attribute__((address_space(3)))
#define FENCE __builtin_amdgcn_sched_barrier(0)

__device__ __forceinline__ unsigned short f2bf(float f) {
  unsigned int u = __float_as_uint(f);
  u += 0x7fffu + ((u >> 16) & 1u);   // RNE
  return (unsigned short)(u >> 16);
}

// ---------- prep 1: W1 [H][U] f32 -> W1T [U][H] bf16 ----------
__global__ void k_transpose_w1(const float* __restrict__ W1, unsigned short* __restrict__ W1T) {
  __shared__ float tile[64][65];
  const int tx = threadIdx.x, ty = threadIdx.y;
  const int u0 = blockIdx.x * 64, h0 = blockIdx.y * 64;
#pragma unroll
  for (int i = 0; i < 16; ++i) {
    int hl = ty + i * 4;
    tile[hl][tx] = W1[(size_t)(h0 + hl) * U_ + (u0 + tx)];
  }
  __syncthreads();
#pragma unroll
  for (int i = 0; i < 16; ++i) {
    int ul = ty + i * 4;
    W1T[(size_t)(u0 + ul) * H_ + (h0 + tx)] = f2bf(tile[tx][ul]);
  }
}

// ---------- prep 2a: qpart[hs][b][u] = sum_{h in strip hs} query[b][h]*W2[h][u] ----------
__global__ void k_b1q_part(const float* __restrict__ query, const float* __restrict__ W2,
                           float* __restrict__ qpart) {
  __shared__ float q_sh[32 * 128];
  const int u = blockIdx.x * 256 + threadIdx.x;
  const int hs = blockIdx.y;                       // 8 strips of 128
  for (int i = threadIdx.x; i < 4096; i += 256) {
    const int b = i >> 7, h = i & 127;
    q_sh[i] = query[b * H_ + hs * 128 + h];
  }
  __syncthreads();
  float acc[32];
#pragma unroll
  for (int b = 0; b < 32; ++b) acc[b] = 0.f;
  for (int h = 0; h < 128; ++h) {
    const float w = W2[(size_t)(hs * 128 + h) * U_ + u];
#pragma unroll
    for (int b = 0; b < 32; ++b) acc[b] += q_sh[b * 128 + h] * w;
  }
#pragma unroll
  for (int b = 0; b < 32; ++b) qpart[((size_t)hs * 32 + b) * U_ + u] = acc[b];
}

// ---------- prep 2b: b1q[b][u] = b1[u]+b2[u]+sum_hs qpart ----------
__global__ void k_b1q_comb(const float* __restrict__ qpart, const float* __restrict__ b1,
                           const float* __restrict__ b2, float* __restrict__ b1q) {
  const int u = blockIdx.x * 256 + threadIdx.x;
  const int b = blockIdx.y;
  float s = b1[u] + b2[u];
#pragma unroll
  for (int hs = 0; hs < 8; ++hs) s += qpart[((size_t)hs * 32 + b) * U_ + u];
  b1q[b * U_ + u] = s;
}

// ---------- fused GEMM+tanh+V: r13 DMA pipeline with f32-A (no k_cvt pass) ----------
// Tile 128x256xBK32, 8 waves (2x4), 2 blocks/CU. LDS 80 KB: Af 2x[128r][32c] f32
// (32 KB) + Bs 3x[256r][32c] bf16 (48 KB). A staged RAW f32 by global_load_lds;
// f32->bf16 conversion at fragment-read time -- removes the 384 MB k_cvt pass.
// r16 BUG (m104/m108): gl_lds dest = wave-uniform base + lane*SIZE; r16 gave each
// thread two chunks at 32B stride -> HW interleaved wrongly. FIX: each instruction
// stages chunk c = j*512+tid at dest byte c*16 (lane-consecutive): rows j*64+(tid>>3),
// phys chunk tid&7, pre-swizzled source lc = (tid&7)^((tid>>3)&7)  [row&7 == (tid>>3)&7
// for both halves since 64%8==0].
// Step t: stage A(t+1)->slot (t+1)&1 (2 gl_lds), B(t+2)->slot (t+2)%3 (2 gl_lds);
// frag-read A slot t&1 / B slot t%3; 16 MFMA; vmcnt(2) [FIFO: retires exactly
// A(t+1)+B(t+1), keeps B(t+2) in flight; vmcnt(0) only at t=30]; s_barrier.
// Swizzles (both-sides involutions, rule 21): A 8 chunks/row, phys = logical^(row&7);
// B 4 chunks/row, phys = logical^((row>>1)&3) (r2-verified 0 conflicts).
#define BM 128
#define BN 256
#define BK 32
#define NSTEP 32   // H_/BK

__global__ __launch_bounds__(512, 4)
void k_fused_score(const float* __restrict__ values,
                   const unsigned short* __restrict__ W1T,
                   const float* __restrict__ b1q, const float* __restrict__ V,
                   float* __restrict__ score_part) {
  __shared__ __align__(16) unsigned char smem[81920];
  float* Af = (float*)smem;                               // [2][128*32] f32
  unsigned short* Bs = (unsigned short*)(smem + 32768);   // [3][256*32] bf16
  float* scorebuf = (float*)smem;                          // alias post-loop

  const int tid = threadIdx.x;
  const int g = blockIdx.x;                  // 2048 = 512 bm x 4 bn
  const int seq = (g & 7) * 256 + (g >> 3);  // bijective XCD swizzle (2048 = 8*256)
  const int bn = seq & 3;
  const int bm = seq >> 2;

  const int lane = tid & 63, wid = tid >> 6;
  const int wm = wid >> 2, wn = wid & 3;     // 2 x 4 waves
  const int u0 = bn * BN;

  // ---- A staging (f32): instruction j covers chunk c = j*512+tid -> row j*64+(tid>>3),
  //      phys chunk tid&7, dest byte c*16 (lane-consecutive x16B).
  const int ar8 = tid >> 3;                  // 0..63
  const int lcA = (tid & 7) ^ (ar8 & 7);     // pre-swizzled logical chunk
  const float* pafA = values + (size_t)(bm * BM + ar8) * H_ + lcA * 4;
  const float* pafB = pafA + (size_t)64 * H_;

  // ---- B staging (bf16, 4-chunk swizzle, r13 verbatim: one chunk/thread/instr)
  const int ar4 = tid >> 2;
  const int blc = (tid & 3) ^ ((ar4 >> 1) & 3);
  const unsigned short* pb0 = W1T + (size_t)(u0 + ar4) * H_ + blc * 8;
  const unsigned short* pb1 = pb0 + (size_t)128 * H_;

  // ---- fragment read offsets ----
  const int l15 = lane & 15, l16 = lane >> 4;
  const int s7 = l15 & 7;
  const int pAf0 = (wm * 64 + l15) * 32 + ((2 * l16)     ^ s7) * 4;  // floats, + mf*512
  const int pAf1 = (wm * 64 + l15) * 32 + ((2 * l16 + 1) ^ s7) * 4;
  const int fsq = ((l16 ^ ((lane >> 1) & 3)) << 3);                  // shorts
  const int pB = (wn * 64 + l15) * 32 + fsq;                         // + nf*512

  f32x4 acc[4][4];
#pragma unroll
  for (int mf = 0; mf < 4; ++mf)
#pragma unroll
    for (int nf = 0; nf < 4; ++nf) acc[mf][nf] = (f32x4){0.f, 0.f, 0.f, 0.f};

#define STAGE_A(tt) { \
    const int sl_ = ((tt) & 1) * 4096; \
    __builtin_amdgcn_global_load_lds((const AS1 void*)(pafA + (size_t)(tt) * BK), \
        (AS3 void*)&Af[sl_ + tid * 4], 16, 0, 0); \
    __builtin_amdgcn_global_load_lds((const AS1 void*)(pafB + (size_t)(tt) * BK), \
        (AS3 void*)&Af[sl_ + 2048 + tid * 4], 16, 0, 0); }

#define STAGE_B(tt) { \
    const int sl_ = ((tt) % 3) * 8192; \
    __builtin_amdgcn_global_load_lds((const AS1 void*)(pb0 + (size_t)(tt) * BK), \
        (AS3 void*)&Bs[sl_ + tid * 8], 16, 0, 0); \
    __builtin_amdgcn_global_load_lds((const AS1 void*)(pb1 + (size_t)(tt) * BK), \
        (AS3 void*)&Bs[sl_ + 4096 + tid * 8], 16, 0, 0); }

  // ---- prologue: A(0)->slot0, B(0)->slot0, B(1)->slot1; vmcnt(2) keeps B(1) in flight
  STAGE_A(0);
  STAGE_B(0);
  STAGE_B(1);
  asm volatile("s_waitcnt vmcnt(2)" ::: "memory");
  FENCE;
  __builtin_amdgcn_s_barrier();

  for (int t = 0; t < NSTEP; ++t) {
    if (t + 1 < NSTEP) STAGE_A(t + 1);
    if (t + 2 < NSTEP) STAGE_B(t + 2);
    FENCE;
    const int aOff = (t & 1) * 4096;       // floats
    const int bOff = (t % 3) * 8192;       // shorts
    short8 bv[4];
#pragma unroll
    for (int nf = 0; nf < 4; ++nf)
      bv[nf] = *(const short8*)&Bs[bOff + pB + nf * 512];
#pragma unroll
    for (int mf = 0; mf < 4; ++mf) {
      const f32x4 a0 = *(const f32x4*)&Af[aOff + pAf0 + mf * 512];
      const f32x4 a1 = *(const f32x4*)&Af[aOff + pAf1 + mf * 512];
      short8 af;
      af[0] = f2bf(a0[0]); af[1] = f2bf(a0[1]); af[2] = f2bf(a0[2]); af[3] = f2bf(a0[3]);
      af[4] = f2bf(a1[0]); af[5] = f2bf(a1[1]); af[6] = f2bf(a1[2]); af[7] = f2bf(a1[3]);
#pragma unroll
      for (int nf = 0; nf < 4; ++nf)
        acc[mf][nf] = __builtin_amdgcn_mfma_f32_16x16x32_bf16(af, bv[nf], acc[mf][nf], 0, 0, 0);
    }
    FENCE;
    if (t + 2 < NSTEP) { asm volatile("s_waitcnt vmcnt(2)" ::: "memory"); }
    else               { asm volatile("s_waitcnt vmcnt(0)" ::: "memory"); }
    FENCE;
    __builtin_amdgcn_s_barrier();
  }

  // ---- epilogue: tanh(acc + b1q) * V, reduce over u ----
  __syncthreads();
  const int b_blk = bm >> 4;                 // 128-row tile never crosses a batch
  float bqv[4], vvv[4];
#pragma unroll
  for (int nf = 0; nf < 4; ++nf) {
    const int ug = u0 + wn * 64 + nf * 16 + l15;   // D col = lane&15
    bqv[nf] = b1q[b_blk * U_ + ug];
    vvv[nf] = V[ug];
  }
  float rp[4][4];
#pragma unroll
  for (int mf = 0; mf < 4; ++mf)
#pragma unroll
    for (int j = 0; j < 4; ++j) rp[mf][j] = 0.f;
#pragma unroll
  for (int nf = 0; nf < 4; ++nf)
#pragma unroll
    for (int mf = 0; mf < 4; ++mf) {
      const f32x4 c = acc[mf][nf];
#pragma unroll
      for (int j = 0; j < 4; ++j) {
        const float x = c[j] + bqv[nf];
        const float e = __expf(2.f * x);     // inf-safe tanh
        const float tt = 1.f - 2.f / (e + 1.f);
        rp[mf][j] += tt * vvv[nf];
      }
    }
#pragma unroll
  for (int mf = 0; mf < 4; ++mf)
#pragma unroll
    for (int j = 0; j < 4; ++j) {
      float v = rp[mf][j];
      v += __shfl_xor(v, 1);
      v += __shfl_xor(v, 2);
      v += __shfl_xor(v, 4);
      v += __shfl_xor(v, 8);
      rp[mf][j] = v;
    }
  if (l15 == 0) {
#pragma unroll
    for (int mf = 0; mf < 4; ++mf)
#pragma unroll
      for (int j = 0; j < 4; ++j)
        scorebuf[(wm * 64 + mf * 16 + l16 * 4 + j) * 4 + wn] = rp[mf][j];
  }
  __syncthreads();
  if (tid < BM) {
    const float s = scorebuf[tid * 4 + 0] + scorebuf[tid * 4 + 1] +
                    scorebuf[tid * 4 + 2] + scorebuf[tid * 4 + 3];
    score_part[(size_t)bn * (B_ * S_) + bm * BM + tid] = s;
  }
}

// ---------- softmax over S per batch (4 u-partials; bV shift-invariant -> dropped) ----------
__global__ void k_softmax(const float* __restrict__ sp, float* __restrict__ aw) {
  __shared__ float red[8];
  const int b = blockIdx.x, tid = threadIdx.x;   // 256 threads, 8 elems each
  const int BS = B_ * S_;
  float x[8];
  float m = -1e30f;
#pragma unroll
  for (int i = 0; i < 8; ++i) {
    const int s = b * S_ + tid + i * 256;
    x[i] = sp[s] + sp[BS + s] + sp[2 * BS + s] + sp[3 * BS + s];
    m = fmaxf(m, x[i]);
  }
#pragma unroll
  for (int off = 32; off; off >>= 1) m = fmaxf(m, __shfl_xor(m, off));
  if ((tid & 63) == 0) red[tid >> 6] = m;
  __syncthreads();
  m = fmaxf(fmaxf(red[0], red[1]), fmaxf(red[2], red[3]));
  float e[8];
  float sum = 0.f;
#pragma unroll
  for (int i = 0; i < 8; ++i) { e[i] = __expf(x[i] - m); sum += e[i]; }
#pragma unroll
  for (int off = 32; off; off >>= 1) sum += __shfl_xor(sum, off);
  __syncthreads();
  if ((tid & 63) == 0) red[4 + (tid >> 6)] = sum;
  __syncthreads();
  sum = red[4] + red[5] + red[6] + red[7];
  const float inv = 1.f / sum;
#pragma unroll
  for (int i = 0; i < 8; ++i) aw[b * S_ + tid + i * 256] = e[i] * inv;
}

// ---------- context: partial weighted sums over 64-row s-chunks (f32), then combine ----------
__global__ void k_ctx_partial(const float* __restrict__ values, const float* __restrict__ aw,
                              float* __restrict__ part) {
  __shared__ float a_s[64];
  const int b = blockIdx.y, sc = blockIdx.x, tid = threadIdx.x;  // 32 chunks x 64 s
  if (tid < 64) a_s[tid] = aw[b * S_ + sc * 64 + tid];
  __syncthreads();
  const float4* vp = (const float4*)values + (size_t)(b * S_ + sc * 64) * (H_ / 4) + tid;
  float4 acc = {0.f, 0.f, 0.f, 0.f};
#pragma unroll 4
  for (int i = 0; i < 64; ++i) {
    const float4 v = vp[(size_t)i * (H_ / 4)];
    const float a = a_s[i];
    acc.x += a * v.x; acc.y += a * v.y; acc.z += a * v.z; acc.w += a * v.w;
  }
  ((float4*)part)[(size_t)(b * 32 + sc) * (H_ / 4) + tid] = acc;
}

__global__ void k_ctx_combine(const float* __restrict__ part, float* __restrict__ ctx) {
  const int b = blockIdx.x, tid = threadIdx.x;
  float4 s = {0.f, 0.f, 0.f, 0.f};
#pragma unroll
  for (int c = 0; c < 32; ++c) {
    const float4 v = ((const float4*)part)[(size_t)(b * 32 + c) * (H_ / 4) + tid];
    s.x += v.x; s.y += v.y; s.z += v.z; s.w += v.w;
  }
  ((float4*)ctx)[b * (H_ / 4) + tid] = s;
}

extern "C" void kernel_launch(void* const* d_in, const int* in_sizes, int n_in,
                              void* d_out, int out_size, void* d_ws, size_t ws_size,
                              hipStream_t stream) {
  const float* query  = (const float*)d_in[0];
  const float* values = (const float*)d_in[1];
  const float* W1     = (const float*)d_in[2];
  const float* b1     = (const float*)d_in[3];
  const float* W2     = (const float*)d_in[4];
  const float* b2     = (const float*)d_in[5];
  const float* V      = (const float*)d_in[6];
  // d_in[7] = bV: softmax shift-invariant, affects neither output -> unused.

  char* ws = (char*)d_ws;
  unsigned short* W1T = (unsigned short*)ws;                                   // 2 MB  [U][H] bf16
  float* b1q   = (float*)(ws + 2u * 1024u * 1024u);                            // 128 KB [B][U]
  float* spart = (float*)(ws + 2u * 1024u * 1024u + 128u * 1024u);             // 1 MB  [4][B*S]
  float* qpart = (float*)(ws + 3u * 1024u * 1024u + 128u * 1024u);             // 1 MB  [8][B][U]
  float* cpart = (float*)(ws + 4u * 1024u * 1024u + 256u * 1024u);             // 4 MB  [B*32][H]

  float* aw  = (float*)d_out;        // [B,S,1]
  float* ctx = aw + B_ * S_;         // [B,H]

  k_transpose_w1<<<dim3(16, 16), dim3(64, 4), 0, stream>>>(W1, W1T);
  k_b1q_part<<<dim3(4, 8), dim3(256), 0, stream>>>(query, W2, qpart);
  k_b1q_comb<<<dim3(4, 32), dim3(256), 0, stream>>>(qpart, b1, b2, b1q);
  k_fused_score<<<dim3(2048), dim3(512), 0, stream>>>(values, W1T, b1q, V, spart);
  k_softmax<<<dim3(32), dim3(256), 0, stream>>>(spart, aw);
  k_ctx_partial<<<dim3(32, 32), dim3(256), 0, stream>>>(values, aw, cpart);
  k_ctx_combine<<<dim3(32), dim3(256), 0, stream>>>(cpart, ctx);
}